// Round 3
// baseline (415.826 us; speedup 1.0000x reference)
//
#include <hip/hip_runtime.h>
#include <hip/hip_fp16.h>

#define M_TOK 512
#define N_OUT 11008
#define K_IN  4096
#define KB    32       // number of k-groups (of 128)
#define SPLITK 4       // K split: each block does 1024 k = 16 iters of BK=64
#define NIT   (K_IN / SPLITK / 64)
// tile: BM=128, BN=128, BK=64; 256 threads = 4 waves, each wave 64x64 (4x4 of 16x16x32)
// grid = 86 (N) x 4 (M) x 4 (Kz) = 1376 blocks ~ 5.4 blocks/CU (LDS-capped at 5)

typedef _Float16 f16x8 __attribute__((ext_vector_type(8)));
typedef _Float16 f16x2 __attribute__((ext_vector_type(2)));
typedef float    f32x4 __attribute__((ext_vector_type(4)));

// ---------------- prep: x fp32 -> f16 (blocks 0..1023) + zero d_out (blocks 1024..6527) ----
__global__ __launch_bounds__(256) void prep_kernel(const float* __restrict__ x,
                                                   _Float16* __restrict__ xh,
                                                   float4* __restrict__ outz) {
    int bid = blockIdx.x;
    if (bid < 1024) {                       // 1024*256*8 = 2,097,152 = 512*4096
        int i = (bid * 256 + threadIdx.x) * 8;
        float4 a = *(const float4*)(x + i);
        float4 b = *(const float4*)(x + i + 4);
        f16x8 v;
        v[0] = (_Float16)a.x; v[1] = (_Float16)a.y; v[2] = (_Float16)a.z; v[3] = (_Float16)a.w;
        v[4] = (_Float16)b.x; v[5] = (_Float16)b.y; v[6] = (_Float16)b.z; v[7] = (_Float16)b.w;
        *(f16x8*)(xh + i) = v;
    } else {                                // 5504*256 float4 = 5,636,096 floats = 512*11008
        int i = (bid - 1024) * 256 + threadIdx.x;
        outz[i] = make_float4(0.f, 0.f, 0.f, 0.f);
    }
}

// async global->LDS, 16B per lane (dest = wave-uniform base + lane*16)
__device__ __forceinline__ void gload_lds16(const void* g, void* l) {
    __builtin_amdgcn_global_load_lds(
        (const __attribute__((address_space(1))) void*)g,
        (__attribute__((address_space(3))) void*)l,
        16, 0, 0);
}

// dequant one byte (2 nibbles) -> packed f16 pair {(lo-z)*s, (hi-z)*s}
__device__ __forceinline__ unsigned int dq_pair(int b, f16x2 fz2, f16x2 ss2) {
    unsigned int u = ((unsigned int)b & 15u) |
                     (((unsigned int)b << 12) & 0xF0000u) |
                     0x64006400u;                       // {1024+lo, 1024+hi} as f16x2
    f16x2 h = __builtin_bit_cast(f16x2, u);
    f16x2 w = (h - fz2) * ss2;                          // exact sub (Sterbenz), one f16 rounding
    return __builtin_bit_cast(unsigned int, w);
}

__global__ __launch_bounds__(256, 5)
void gemm_w4_kernel(const int* __restrict__ qw,      // (N, 32, 64) int32, 1 byte each
                    const float* __restrict__ scales, // flat N*32
                    const int* __restrict__ qz,       // flat N*32/2 bytes (nibble pairs)
                    const _Float16* __restrict__ xh,  // (M, K) f16
                    float* __restrict__ out) {        // (M, N) f32, pre-zeroed, atomicAdd
    __shared__ __align__(16) char As[128 * 128];  // 128 m-rows x 64 k x 2B, XOR-swizzled
    __shared__ __align__(16) char Bs[128 * 128];  // 128 n-rows x 64 k x 2B

    // ---- XCD-chunked bijective swizzle; logical order: mx fastest so the 4
    // same-(ny,kz) M-sharers sit on one XCD and share the qweight slice in L2.
    const int hw  = blockIdx.x;            // 0..1375; 1376 = 8*172, 172%4==0
    const int logical = (hw & 7) * 172 + (hw >> 3);
    const int mx = logical & 3;
    const int rest = logical >> 2;
    const int ny = rest % 86;
    const int kz = rest / 86;

    const int n0 = ny * 128;
    const int m0 = mx * 128;

    const int tid  = threadIdx.x;
    const int lane = tid & 63;
    const int wid  = tid >> 6;
    const int wm   = wid >> 1;      // wave m index (0..1)
    const int wn   = wid & 1;       // wave n index (0..1)
    const int r16  = lane & 15;
    const int g4   = lane >> 4;

    // ---- A staging: 4 x global_load_lds (16B/lane) per iter; pre-swizzled source ----
    const char* xbytes = (const char*)xh;
    const char* asrc[4];
#pragma unroll
    for (int i = 0; i < 4; ++i) {
        int row = (tid >> 3) + i * 32;          // LDS row this thread's chunk lands in
        int cb  = (tid & 7) * 16;               // phys col-byte
        int cbl = cb ^ ((row & 7) << 4);        // logical col-byte (inverse swizzle)
        asrc[i] = xbytes + (size_t)(m0 + row) * (K_IN * 2) + kz * 2048 + cbl;
    }

    // ---- B decode assignment: thread -> n_loc = tid>>1, half = tid&1 ----
    const int n_loc = tid >> 1;
    const int half  = tid & 1;
    const int n_g   = n0 + n_loc;
    const int4* qbase = (const int4*)qw + ((size_t)n_g * 512 + kz * 128 + half * 4);
    const int fbase = n_g * KB + kz * 8;       // scale/zero group base for this K-range
    unsigned int waddr[4];
#pragma unroll
    for (int q4 = 0; q4 < 4; ++q4) {
        int kt2 = half * 64 + q4 * 16;          // byte offset of 8-f16 chunk within row
        waddr[q4] = n_loc * 128 + (kt2 ^ ((n_loc & 7) << 4));
    }

    f32x4 acc[4][4];
#pragma unroll
    for (int mi = 0; mi < 4; ++mi)
#pragma unroll
        for (int ni = 0; ni < 4; ++ni)
            acc[mi][ni] = (f32x4){0.f, 0.f, 0.f, 0.f};

#pragma unroll 2
    for (int it = 0; it < NIT; ++it) {
        // issue qweight loads early (global only, no LDS hazard)
        int4 qv0 = qbase[it * 8 + 0];
        int4 qv1 = qbase[it * 8 + 1];
        int4 qv2 = qbase[it * 8 + 2];
        int4 qv3 = qbase[it * 8 + 3];

        // per-group (s, z): it>>1 is loop-pair-invariant -> CSE'd by unroll 2
        const int f  = fbase + (it >> 1);
        const float s  = scales[f];
        const int  zb  = qz[f >> 1];
        const int  z   = (zb >> ((f & 1) * 4)) & 15;
        const _Float16 sh = (_Float16)s;
        const _Float16 fzh = (_Float16)(float)(1024 + z);
        const f16x2 ss2 = (f16x2){sh, sh};
        const f16x2 fz2 = (f16x2){fzh, fzh};

        __syncthreads();  // previous compute done reading LDS

        // A tile: 16 KB via async direct-to-LDS
#pragma unroll
        for (int i = 0; i < 4; ++i)
            gload_lds16(asrc[i] + it * 128, As + (wid * 64 + i * 256) * 16);

        // B tile: decode 16 bytes -> 32 f16, swizzled ds_write_b128 x4
        {
            uint4 w;
            w.x = dq_pair(qv0.x, fz2, ss2); w.y = dq_pair(qv0.y, fz2, ss2);
            w.z = dq_pair(qv0.z, fz2, ss2); w.w = dq_pair(qv0.w, fz2, ss2);
            *(uint4*)(Bs + waddr[0]) = w;
            w.x = dq_pair(qv1.x, fz2, ss2); w.y = dq_pair(qv1.y, fz2, ss2);
            w.z = dq_pair(qv1.z, fz2, ss2); w.w = dq_pair(qv1.w, fz2, ss2);
            *(uint4*)(Bs + waddr[1]) = w;
            w.x = dq_pair(qv2.x, fz2, ss2); w.y = dq_pair(qv2.y, fz2, ss2);
            w.z = dq_pair(qv2.z, fz2, ss2); w.w = dq_pair(qv2.w, fz2, ss2);
            *(uint4*)(Bs + waddr[2]) = w;
            w.x = dq_pair(qv3.x, fz2, ss2); w.y = dq_pair(qv3.y, fz2, ss2);
            w.z = dq_pair(qv3.z, fz2, ss2); w.w = dq_pair(qv3.w, fz2, ss2);
            *(uint4*)(Bs + waddr[3]) = w;
        }

        __syncthreads();  // staged data visible

        // compute: 2 k-halves x 4x4 MFMA
#pragma unroll
        for (int kh = 0; kh < 2; ++kh) {
            f16x8 af[4], bf[4];
#pragma unroll
            for (int mi = 0; mi < 4; ++mi) {
                int row = wm * 64 + mi * 16 + r16;
                int off = row * 128 + ((kh * 64 + g4 * 16) ^ ((row & 7) << 4));
                af[mi] = *(const f16x8*)(As + off);
            }
#pragma unroll
            for (int ni = 0; ni < 4; ++ni) {
                int row = wn * 64 + ni * 16 + r16;
                int off = row * 128 + ((kh * 64 + g4 * 16) ^ ((row & 7) << 4));
                bf[ni] = *(const f16x8*)(Bs + off);
            }
#pragma unroll
            for (int mi = 0; mi < 4; ++mi)
#pragma unroll
                for (int ni = 0; ni < 4; ++ni)
                    acc[mi][ni] = __builtin_amdgcn_mfma_f32_16x16x32_f16(
                        af[mi], bf[ni], acc[mi][ni], 0, 0, 0);
        }
    }

    // epilogue: D col = lane&15, row = (lane>>4)*4 + reg; split-K accumulate
#pragma unroll
    for (int mi = 0; mi < 4; ++mi) {
#pragma unroll
        for (int ni = 0; ni < 4; ++ni) {
            const int col   = n0 + wn * 64 + ni * 16 + r16;
            const int rbase = m0 + wm * 64 + mi * 16 + g4 * 4;
            f32x4 v = acc[mi][ni];
#pragma unroll
            for (int r = 0; r < 4; ++r)
                unsafeAtomicAdd(&out[(size_t)(rbase + r) * N_OUT + col], v[r]);
        }
    }
}

extern "C" void kernel_launch(void* const* d_in, const int* in_sizes, int n_in,
                              void* d_out, int out_size, void* d_ws, size_t ws_size,
                              hipStream_t stream) {
    const float* x  = (const float*)d_in[0];
    const int*   qw = (const int*)d_in[1];
    const float* sc = (const float*)d_in[2];
    const int*   qz = (const int*)d_in[3];
    _Float16*    xh = (_Float16*)d_ws;     // 512*4096*2 = 4 MB scratch
    float*       out = (float*)d_out;

    // fused prep: x -> f16 (1024 blocks) + zero out (5504 blocks)
    prep_kernel<<<dim3(1024 + 5504), 256, 0, stream>>>(x, xh, (float4*)out);

    // fused dequant GEMM, split-K=4: 86*4*4 = 1376 blocks, XCD-swizzled in-kernel
    gemm_w4_kernel<<<dim3(1376), 256, 0, stream>>>(qw, sc, qz, xh, out);
}

// Round 5
// 397.374 us; speedup vs baseline: 1.0464x; 1.0464x over previous
//
#include <hip/hip_runtime.h>
#include <hip/hip_fp16.h>

#define M_TOK 512
#define N_OUT 11008
#define K_IN  4096
#define KB    32       // number of k-groups (of 128)
// tile: BM=128, BN=128, BK=64; 256 threads = 4 waves, each wave 64x64 (4x4 of 16x16x32)
// split-K via private f32 partials in d_ws + reduce pass (NO atomics — R3 lesson)

typedef _Float16 f16x8 __attribute__((ext_vector_type(8)));
typedef _Float16 f16x2 __attribute__((ext_vector_type(2)));
typedef float    f32x4 __attribute__((ext_vector_type(4)));

// ---------------- prep: x fp32 -> f16 ----------------
__global__ __launch_bounds__(256) void cvt_x_kernel(const float* __restrict__ x,
                                                    _Float16* __restrict__ xh) {
    int i = (blockIdx.x * 256 + threadIdx.x) * 8;
    float4 a = *(const float4*)(x + i);
    float4 b = *(const float4*)(x + i + 4);
    f16x8 v;
    v[0] = (_Float16)a.x; v[1] = (_Float16)a.y; v[2] = (_Float16)a.z; v[3] = (_Float16)a.w;
    v[4] = (_Float16)b.x; v[5] = (_Float16)b.y; v[6] = (_Float16)b.z; v[7] = (_Float16)b.w;
    *(f16x8*)(xh + i) = v;
}

// ---------------- reduce: out = sum over splitk partials ----------------
__global__ __launch_bounds__(256) void reduce_kernel(const float4* __restrict__ part,
                                                     float4* __restrict__ out, int splitk) {
    const size_t stride4 = (size_t)M_TOK * N_OUT / 4;
    size_t i = (size_t)blockIdx.x * 256 + threadIdx.x;
    float4 a = part[i];
    for (int s = 1; s < splitk; ++s) {
        float4 b = part[i + (size_t)s * stride4];
        a.x += b.x; a.y += b.y; a.z += b.z; a.w += b.w;
    }
    out[i] = a;
}

// async global->LDS, 16B per lane (dest = wave-uniform base + lane*16)
__device__ __forceinline__ void gload_lds16(const void* g, void* l) {
    __builtin_amdgcn_global_load_lds(
        (const __attribute__((address_space(1))) void*)g,
        (__attribute__((address_space(3))) void*)l,
        16, 0, 0);
}

// dequant one byte (2 nibbles) -> packed f16 pair {(lo-z)*s, (hi-z)*s}
__device__ __forceinline__ unsigned int dq_pair(int b, f16x2 fz2, f16x2 ss2) {
    unsigned int u = ((unsigned int)b & 15u) |
                     (((unsigned int)b << 12) & 0xF0000u) |
                     0x64006400u;                       // {1024+lo, 1024+hi} as f16x2
    f16x2 h = __builtin_bit_cast(f16x2, u);
    f16x2 w = (h - fz2) * ss2;                          // exact sub (Sterbenz), one f16 rounding
    return __builtin_bit_cast(unsigned int, w);
}

// KITER = K-iterations (of BK=64) per block; SPLITK = 64/KITER
template<int KITER>
__global__ __launch_bounds__(256, 5)
void gemm_w4_kernel(const int* __restrict__ qw,      // (N, 32, 64) int32, 1 byte each
                    const float* __restrict__ scales, // flat N*32
                    const int* __restrict__ qz,       // flat N*32/2 bytes (nibble pairs)
                    const _Float16* __restrict__ xh,  // (M, K) f16
                    float* __restrict__ outp) {       // partials (kz,M,N) or out (M,N)
    constexpr int SPLITK_ = 64 / KITER;
    __shared__ __align__(16) char As[128 * 128];  // 128 m-rows x 64 k x 2B, XOR-swizzled
    __shared__ __align__(16) char Bs[128 * 128];  // 128 n-rows x 64 k x 2B

    // XCD-chunked bijective swizzle (grid = 344*SPLITK_, divisible by 8);
    // logical order mx-fastest: the 4 same-(ny,kz) M-sharers land on one XCD -> qweight L2 reuse
    const int total = 344 * SPLITK_;
    const int chunk = total >> 3;
    const int hw  = blockIdx.x;
    const int logical = (hw & 7) * chunk + (hw >> 3);
    const int mx = logical & 3;
    const int rest = logical >> 2;
    const int ny = rest % 86;
    const int kz = rest / 86;

    const int n0 = ny * 128;
    const int m0 = mx * 128;

    const int tid  = threadIdx.x;
    const int lane = tid & 63;
    const int wid  = tid >> 6;
    const int wm   = wid >> 1;      // wave m index (0..1)
    const int wn   = wid & 1;       // wave n index (0..1)
    const int r16  = lane & 15;
    const int g4   = lane >> 4;

    // ---- A staging: 4 x global_load_lds (16B/lane) per iter; pre-swizzled source ----
    const char* xbytes = (const char*)xh;
    const char* asrc[4];
#pragma unroll
    for (int i = 0; i < 4; ++i) {
        int row = (tid >> 3) + i * 32;          // LDS row this thread's chunk lands in
        int cb  = (tid & 7) * 16;               // phys col-byte
        int cbl = cb ^ ((row & 7) << 4);        // logical col-byte (inverse swizzle)
        asrc[i] = xbytes + (size_t)(m0 + row) * (K_IN * 2) + kz * (KITER * 128) + cbl;
    }

    // ---- B decode assignment: thread -> n_loc = tid>>1, half = tid&1 ----
    const int n_loc = tid >> 1;
    const int half  = tid & 1;
    const int n_g   = n0 + n_loc;
    const int4* qbase = (const int4*)qw + ((size_t)n_g * 512 + kz * (KITER * 8) + half * 4);
    const int fbase = n_g * KB + kz * (KITER / 2);   // scale/zero group base for this K-range
    unsigned int waddr[4];
#pragma unroll
    for (int q4 = 0; q4 < 4; ++q4) {
        int kt2 = half * 64 + q4 * 16;          // byte offset of 8-f16 chunk within row
        waddr[q4] = n_loc * 128 + (kt2 ^ ((n_loc & 7) << 4));
    }

    f32x4 acc[4][4];
#pragma unroll
    for (int mi = 0; mi < 4; ++mi)
#pragma unroll
        for (int ni = 0; ni < 4; ++ni)
            acc[mi][ni] = (f32x4){0.f, 0.f, 0.f, 0.f};

#pragma unroll 2
    for (int it = 0; it < KITER; ++it) {
        // issue qweight loads early (global only, no LDS hazard)
        int4 qv0 = qbase[it * 8 + 0];
        int4 qv1 = qbase[it * 8 + 1];
        int4 qv2 = qbase[it * 8 + 2];
        int4 qv3 = qbase[it * 8 + 3];

        // per-group (s, z): it>>1 is loop-pair-invariant -> CSE'd by unroll 2
        const int f  = fbase + (it >> 1);
        const float s  = scales[f];
        const int  zb  = qz[f >> 1];
        const int  z   = (zb >> ((f & 1) * 4)) & 15;
        const _Float16 sh = (_Float16)s;
        const _Float16 fzh = (_Float16)(float)(1024 + z);
        const f16x2 ss2 = (f16x2){sh, sh};
        const f16x2 fz2 = (f16x2){fzh, fzh};

        __syncthreads();  // previous compute done reading LDS

        // A tile: 16 KB via async direct-to-LDS
#pragma unroll
        for (int i = 0; i < 4; ++i)
            gload_lds16(asrc[i] + it * 128, As + (wid * 64 + i * 256) * 16);

        // B tile: decode 16 bytes -> 32 f16, swizzled ds_write_b128 x4
        {
            uint4 w;
            w.x = dq_pair(qv0.x, fz2, ss2); w.y = dq_pair(qv0.y, fz2, ss2);
            w.z = dq_pair(qv0.z, fz2, ss2); w.w = dq_pair(qv0.w, fz2, ss2);
            *(uint4*)(Bs + waddr[0]) = w;
            w.x = dq_pair(qv1.x, fz2, ss2); w.y = dq_pair(qv1.y, fz2, ss2);
            w.z = dq_pair(qv1.z, fz2, ss2); w.w = dq_pair(qv1.w, fz2, ss2);
            *(uint4*)(Bs + waddr[1]) = w;
            w.x = dq_pair(qv2.x, fz2, ss2); w.y = dq_pair(qv2.y, fz2, ss2);
            w.z = dq_pair(qv2.z, fz2, ss2); w.w = dq_pair(qv2.w, fz2, ss2);
            *(uint4*)(Bs + waddr[2]) = w;
            w.x = dq_pair(qv3.x, fz2, ss2); w.y = dq_pair(qv3.y, fz2, ss2);
            w.z = dq_pair(qv3.z, fz2, ss2); w.w = dq_pair(qv3.w, fz2, ss2);
            *(uint4*)(Bs + waddr[3]) = w;
        }

        __syncthreads();  // staged data visible

        // compute: 2 k-halves x 4x4 MFMA
#pragma unroll
        for (int kh = 0; kh < 2; ++kh) {
            f16x8 af[4], bf[4];
#pragma unroll
            for (int mi = 0; mi < 4; ++mi) {
                int row = wm * 64 + mi * 16 + r16;
                int off = row * 128 + ((kh * 64 + g4 * 16) ^ ((row & 7) << 4));
                af[mi] = *(const f16x8*)(As + off);
            }
#pragma unroll
            for (int ni = 0; ni < 4; ++ni) {
                int row = wn * 64 + ni * 16 + r16;
                int off = row * 128 + ((kh * 64 + g4 * 16) ^ ((row & 7) << 4));
                bf[ni] = *(const f16x8*)(Bs + off);
            }
#pragma unroll
            for (int mi = 0; mi < 4; ++mi)
#pragma unroll
                for (int ni = 0; ni < 4; ++ni)
                    acc[mi][ni] = __builtin_amdgcn_mfma_f32_16x16x32_f16(
                        af[mi], bf[ni], acc[mi][ni], 0, 0, 0);
        }
    }

    // epilogue: D col = lane&15, row = (lane>>4)*4 + reg; plain stores to private partial
    float* obase = outp + (size_t)kz * ((size_t)M_TOK * N_OUT);
#pragma unroll
    for (int mi = 0; mi < 4; ++mi) {
#pragma unroll
        for (int ni = 0; ni < 4; ++ni) {
            const int col   = n0 + wn * 64 + ni * 16 + r16;
            const int rbase = m0 + wm * 64 + mi * 16 + g4 * 4;
            f32x4 v = acc[mi][ni];
#pragma unroll
            for (int r = 0; r < 4; ++r)
                obase[(size_t)(rbase + r) * N_OUT + col] = v[r];
        }
    }
}

extern "C" void kernel_launch(void* const* d_in, const int* in_sizes, int n_in,
                              void* d_out, int out_size, void* d_ws, size_t ws_size,
                              hipStream_t stream) {
    const float* x  = (const float*)d_in[0];
    const int*   qw = (const int*)d_in[1];
    const float* sc = (const float*)d_in[2];
    const int*   qz = (const int*)d_in[3];
    float*       out = (float*)d_out;

    const size_t XH_BYTES   = (size_t)M_TOK * K_IN * 2;        // 4 MB
    const size_t PART_BYTES = (size_t)M_TOK * N_OUT * 4;       // 22.5 MB per split
    _Float16* xh   = (_Float16*)d_ws;
    float*    part = (float*)((char*)d_ws + XH_BYTES);

    // split-K factor chosen from ws capacity (constant across calls -> capture-safe)
    int splitk = 1;
    if      (ws_size >= XH_BYTES + 4 * PART_BYTES) splitk = 4;
    else if (ws_size >= XH_BYTES + 2 * PART_BYTES) splitk = 2;

    // x -> f16 (2M elements, 8 per thread)
    cvt_x_kernel<<<dim3((M_TOK * K_IN) / (256 * 8)), 256, 0, stream>>>(x, xh);

    if (splitk == 4) {
        gemm_w4_kernel<16><<<dim3(344 * 4), 256, 0, stream>>>(qw, sc, qz, xh, part);
        reduce_kernel<<<dim3((M_TOK * N_OUT) / (256 * 4)), 256, 0, stream>>>(
            (const float4*)part, (float4*)out, 4);
    } else if (splitk == 2) {
        gemm_w4_kernel<32><<<dim3(344 * 2), 256, 0, stream>>>(qw, sc, qz, xh, part);
        reduce_kernel<<<dim3((M_TOK * N_OUT) / (256 * 4)), 256, 0, stream>>>(
            (const float4*)part, (float4*)out, 2);
    } else {
        gemm_w4_kernel<64><<<dim3(344), 256, 0, stream>>>(qw, sc, qz, xh, out);
    }
}

// Round 7
// 233.804 us; speedup vs baseline: 1.7785x; 1.6996x over previous
//
#include <hip/hip_runtime.h>
#include <hip/hip_fp16.h>

#define M_TOK 512
#define N_OUT 11008
#define K_IN  4096
#define KB    32       // number of k-groups (of 128)
// tile: BM=128, BN=64, BK=64; 256 threads = 4 waves (2x2), wave-tile 64m x 32n
// grid = 172 (N) x 4 (M) = 688 blocks ~ 2.7 blocks/CU (LDS 24 KB, cap 6)
// NO split-K, NO global partials (R3/R5 lesson: partials cost 480 MB HBM writes)

typedef _Float16 f16x8 __attribute__((ext_vector_type(8)));
typedef _Float16 f16x2 __attribute__((ext_vector_type(2)));
typedef float    f32x4 __attribute__((ext_vector_type(4)));

// ---------------- prep: x fp32 -> f16 ----------------
__global__ __launch_bounds__(256) void cvt_x_kernel(const float* __restrict__ x,
                                                    _Float16* __restrict__ xh) {
    int i = (blockIdx.x * 256 + threadIdx.x) * 8;
    float4 a = *(const float4*)(x + i);
    float4 b = *(const float4*)(x + i + 4);
    f16x8 v;
    v[0] = (_Float16)a.x; v[1] = (_Float16)a.y; v[2] = (_Float16)a.z; v[3] = (_Float16)a.w;
    v[4] = (_Float16)b.x; v[5] = (_Float16)b.y; v[6] = (_Float16)b.z; v[7] = (_Float16)b.w;
    *(f16x8*)(xh + i) = v;
}

// async global->LDS, 16B per lane (dest = wave-uniform base + lane*16)
__device__ __forceinline__ void gload_lds16(const void* g, void* l) {
    __builtin_amdgcn_global_load_lds(
        (const __attribute__((address_space(1))) void*)g,
        (__attribute__((address_space(3))) void*)l,
        16, 0, 0);
}

// dequant one byte (2 nibbles) -> packed f16 pair {(lo-z)*s, (hi-z)*s}
__device__ __forceinline__ unsigned int dq_pair(int b, f16x2 fz2, f16x2 ss2) {
    unsigned int u = ((unsigned int)b & 15u) |
                     (((unsigned int)b << 12) & 0xF0000u) |
                     0x64006400u;                       // {1024+lo, 1024+hi} as f16x2
    f16x2 h = __builtin_bit_cast(f16x2, u);
    f16x2 w = (h - fz2) * ss2;                          // exact sub (Sterbenz), one f16 rounding
    return __builtin_bit_cast(unsigned int, w);
}

__global__ __launch_bounds__(256, 4)
void gemm_w4_kernel(const int* __restrict__ qw,      // (N, 32, 64) int32, 1 byte each
                    const float* __restrict__ scales, // flat N*32
                    const int* __restrict__ qz,       // flat N*32/2 bytes (nibble pairs)
                    const _Float16* __restrict__ xh,  // (M, K) f16
                    float* __restrict__ out) {        // (M, N) f32, direct write
    __shared__ __align__(16) char As[128 * 128];  // 128 m-rows x 64 k x 2B, XOR-swizzled
    __shared__ __align__(16) char Bs[64 * 128];   //  64 n-rows x 64 k x 2B

    // XCD-chunked bijective swizzle: 688 = 8*86; logical order mx-fastest so the
    // 4 same-ny qweight-sharers are CONSECUTIVE -> same XCD -> L2 reuse of qweight.
    const int hw  = blockIdx.x;
    const int logical = (hw & 7) * 86 + (hw >> 3);
    const int mx = logical & 3;
    const int ny = logical >> 2;        // 0..171

    const int n0 = ny * 64;
    const int m0 = mx * 128;

    const int tid  = threadIdx.x;
    const int lane = tid & 63;
    const int wid  = tid >> 6;
    const int wm   = wid >> 1;      // wave m index (0..1), tile 64 rows
    const int wn   = wid & 1;       // wave n index (0..1), tile 32 cols
    const int r16  = lane & 15;
    const int g4   = lane >> 4;

    // ---- A staging: 4 x global_load_lds (16B/lane) per iter; pre-swizzled source ----
    const char* xbytes = (const char*)xh;
    const char* asrc[4];
#pragma unroll
    for (int i = 0; i < 4; ++i) {
        int row = (tid >> 3) + i * 32;          // LDS row this thread's chunk lands in
        int cb  = (tid & 7) * 16;               // phys col-byte
        int cbl = cb ^ ((row & 7) << 4);        // logical col-byte (inverse swizzle)
        asrc[i] = xbytes + (size_t)(m0 + row) * (K_IN * 2) + cbl;
    }

    // ---- B decode assignment: thread -> n_loc = tid>>2, q = tid&3 (8 bytes = 16 k) ----
    const int n_loc = tid >> 2;                 // 0..63
    const int q     = tid & 3;
    const int n_g   = n0 + n_loc;
    const int4* qbase = (const int4*)qw + ((size_t)n_g * 512 + q * 2);
    const int fbase = n_g * KB;
    unsigned int waddr[2];
#pragma unroll
    for (int j = 0; j < 2; ++j) {
        int kt2 = q * 32 + j * 16;              // byte offset of 8-f16 chunk within row
        waddr[j] = n_loc * 128 + (kt2 ^ ((n_loc & 7) << 4));
    }

    f32x4 acc[4][2];
#pragma unroll
    for (int mi = 0; mi < 4; ++mi)
#pragma unroll
        for (int ni = 0; ni < 2; ++ni)
            acc[mi][ni] = (f32x4){0.f, 0.f, 0.f, 0.f};

#pragma unroll 2
    for (int it = 0; it < K_IN / 64; ++it) {
        // issue qweight loads early (global only, no LDS hazard)
        int4 qv0 = qbase[it * 8 + 0];
        int4 qv1 = qbase[it * 8 + 1];

        // per-group (s, z): it>>1 is loop-pair-invariant -> CSE'd by unroll 2
        const int f  = fbase + (it >> 1);
        const float s  = scales[f];
        const int  zb  = qz[f >> 1];
        const int  z   = (zb >> ((f & 1) * 4)) & 15;
        const _Float16 sh = (_Float16)s;
        const _Float16 fzh = (_Float16)(float)(1024 + z);
        const f16x2 ss2 = (f16x2){sh, sh};
        const f16x2 fz2 = (f16x2){fzh, fzh};

        __syncthreads();  // previous compute done reading LDS

        // A tile: 16 KB via async direct-to-LDS
#pragma unroll
        for (int i = 0; i < 4; ++i)
            gload_lds16(asrc[i] + it * 128, As + (wid * 64 + i * 256) * 16);

        // B tile: decode 8 bytes -> 16 f16, swizzled ds_write_b128 x2
        {
            uint4 w;
            w.x = dq_pair(qv0.x, fz2, ss2); w.y = dq_pair(qv0.y, fz2, ss2);
            w.z = dq_pair(qv0.z, fz2, ss2); w.w = dq_pair(qv0.w, fz2, ss2);
            *(uint4*)(Bs + waddr[0]) = w;
            w.x = dq_pair(qv1.x, fz2, ss2); w.y = dq_pair(qv1.y, fz2, ss2);
            w.z = dq_pair(qv1.z, fz2, ss2); w.w = dq_pair(qv1.w, fz2, ss2);
            *(uint4*)(Bs + waddr[1]) = w;
        }

        __syncthreads();  // staged data visible

        // compute: 2 k-halves x 4x2 MFMA
#pragma unroll
        for (int kh = 0; kh < 2; ++kh) {
            f16x8 af[4], bf[2];
#pragma unroll
            for (int mi = 0; mi < 4; ++mi) {
                int row = wm * 64 + mi * 16 + r16;
                int off = row * 128 + ((kh * 64 + g4 * 16) ^ ((row & 7) << 4));
                af[mi] = *(const f16x8*)(As + off);
            }
#pragma unroll
            for (int ni = 0; ni < 2; ++ni) {
                int row = wn * 32 + ni * 16 + r16;
                int off = row * 128 + ((kh * 64 + g4 * 16) ^ ((row & 7) << 4));
                bf[ni] = *(const f16x8*)(Bs + off);
            }
#pragma unroll
            for (int mi = 0; mi < 4; ++mi)
#pragma unroll
                for (int ni = 0; ni < 2; ++ni)
                    acc[mi][ni] = __builtin_amdgcn_mfma_f32_16x16x32_f16(
                        af[mi], bf[ni], acc[mi][ni], 0, 0, 0);
        }
    }

    // epilogue: D col = lane&15, row = (lane>>4)*4 + reg; direct coalesced stores
#pragma unroll
    for (int mi = 0; mi < 4; ++mi) {
#pragma unroll
        for (int ni = 0; ni < 2; ++ni) {
            const int col   = n0 + wn * 32 + ni * 16 + r16;
            const int rbase = m0 + wm * 64 + mi * 16 + g4 * 4;
            f32x4 v = acc[mi][ni];
#pragma unroll
            for (int r = 0; r < 4; ++r)
                out[(size_t)(rbase + r) * N_OUT + col] = v[r];
        }
    }
}

extern "C" void kernel_launch(void* const* d_in, const int* in_sizes, int n_in,
                              void* d_out, int out_size, void* d_ws, size_t ws_size,
                              hipStream_t stream) {
    const float* x  = (const float*)d_in[0];
    const int*   qw = (const int*)d_in[1];
    const float* sc = (const float*)d_in[2];
    const int*   qz = (const int*)d_in[3];
    _Float16*    xh = (_Float16*)d_ws;     // 512*4096*2 = 4 MB scratch
    float*       out = (float*)d_out;

    // x -> f16 (2M elements, 8 per thread)
    cvt_x_kernel<<<dim3((M_TOK * K_IN) / (256 * 8)), 256, 0, stream>>>(x, xh);

    // fused dequant GEMM: 172 x 4 = 688 blocks, XCD-swizzled in-kernel, direct out
    gemm_w4_kernel<<<dim3(688), 256, 0, stream>>>(qw, sc, qz, xh, out);
}